// Round 1
// baseline (1657.198 us; speedup 1.0000x reference)
//
#include <hip/hip_runtime.h>
#include <math.h>

#define NN 20000        // nodes
#define NE 320000       // edges
#define NREL 9
#define NBASES 9
#define D_IN 128
#define D_HID 256
#define D_OUT 64
#define LN_EPS 1e-5f

// ---------- monotonic float <-> u32 encoding for atomic max ----------
__device__ inline unsigned fenc(float f) {
    unsigned u = __float_as_uint(f);
    return (u & 0x80000000u) ? ~u : (u | 0x80000000u);
}
__device__ inline float fdec(unsigned u) {
    return __uint_as_float((u & 0x80000000u) ? (u ^ 0x80000000u) : ~u);
}
#define ENC_NEGINF 0x007FFFFFu   // fenc(-inf)

// ---------- W_r = sum_b comp[r,b] * bases[b] (both layers in one kernel) ----------
__global__ __launch_bounds__(256) void compute_w(
    const float* __restrict__ bases1, const float* __restrict__ comp1,
    const float* __restrict__ bases2, const float* __restrict__ comp2,
    float* __restrict__ w1, float* __restrict__ w2)
{
    const int SZ1 = NREL * D_IN * D_HID;    // 294912
    const int SZ2 = NREL * D_HID * D_OUT;   // 147456
    int i = blockIdx.x * 256 + threadIdx.x;
    if (i < SZ1) {
        int r = i / (D_IN * D_HID), io = i % (D_IN * D_HID);
        float s = 0.f;
        #pragma unroll
        for (int b = 0; b < NBASES; b++) s += comp1[r * NBASES + b] * bases1[b * D_IN * D_HID + io];
        w1[i] = s;
    } else if (i < SZ1 + SZ2) {
        int j = i - SZ1;
        int r = j / (D_HID * D_OUT), io = j % (D_HID * D_OUT);
        float s = 0.f;
        #pragma unroll
        for (int b = 0; b < NBASES; b++) s += comp2[r * NBASES + b] * bases2[b * D_HID * D_OUT + io];
        w2[j] = s;
    }
}

__global__ __launch_bounds__(256) void fill_u32(unsigned* __restrict__ p, unsigned v, int n)
{
    int i = blockIdx.x * 256 + threadIdx.x;
    if (i < n) p[i] = v;
}

// ---------- fp32 tiled GEMM: C[M,N] = A[M,K] @ B[K,N], N%64==0, K%32==0 ----------
__global__ __launch_bounds__(256) void gemm_f32(
    const float* __restrict__ A, const float* __restrict__ B, float* __restrict__ C,
    int M, int N, int K)
{
    __shared__ float As[64][36];   // [m][k], +4 pad keeps float4 rows 16B aligned
    __shared__ float Bs[32][68];   // [k][n], +4 pad

    int tid = threadIdx.x;
    int tx = tid & 15, ty = tid >> 4;
    int row0 = blockIdx.y * 64, col0 = blockIdx.x * 64;

    int am = tid >> 3;          // 0..31
    int ak = (tid & 7) * 4;     // 0..28
    int bk = tid >> 4;          // 0..15
    int bn = (tid & 15) * 4;    // 0..60

    float acc[4][4] = {};

    for (int k0 = 0; k0 < K; k0 += 32) {
        #pragma unroll
        for (int i = 0; i < 2; i++) {
            int m = am + i * 32;
            int gr = row0 + m;
            float4 a = make_float4(0.f, 0.f, 0.f, 0.f);
            if (gr < M) a = *(const float4*)&A[(size_t)gr * K + k0 + ak];
            *(float4*)&As[m][ak] = a;
        }
        #pragma unroll
        for (int i = 0; i < 2; i++) {
            int k = bk + i * 16;
            float4 b = *(const float4*)&B[(size_t)(k0 + k) * N + col0 + bn];
            *(float4*)&Bs[k][bn] = b;
        }
        __syncthreads();

        #pragma unroll
        for (int kk = 0; kk < 32; kk += 4) {
            float4 a[4], b[4];
            #pragma unroll
            for (int j = 0; j < 4; j++) a[j] = *(float4*)&As[ty * 4 + j][kk];
            #pragma unroll
            for (int j = 0; j < 4; j++) b[j] = *(float4*)&Bs[kk + j][tx * 4];
            #pragma unroll
            for (int i = 0; i < 4; i++) {
                acc[i][0] += a[i].x * b[0].x; acc[i][1] += a[i].x * b[0].y;
                acc[i][2] += a[i].x * b[0].z; acc[i][3] += a[i].x * b[0].w;
                acc[i][0] += a[i].y * b[1].x; acc[i][1] += a[i].y * b[1].y;
                acc[i][2] += a[i].y * b[1].z; acc[i][3] += a[i].y * b[1].w;
                acc[i][0] += a[i].z * b[2].x; acc[i][1] += a[i].z * b[2].y;
                acc[i][2] += a[i].z * b[2].z; acc[i][3] += a[i].z * b[2].w;
                acc[i][0] += a[i].w * b[3].x; acc[i][1] += a[i].w * b[3].y;
                acc[i][2] += a[i].w * b[3].z; acc[i][3] += a[i].w * b[3].w;
            }
        }
        __syncthreads();
    }

    #pragma unroll
    for (int i = 0; i < 4; i++) {
        int gr = row0 + ty * 4 + i;
        if (gr < M) {
            float4 o = make_float4(acc[i][0], acc[i][1], acc[i][2], acc[i][3]);
            *(float4*)&C[(size_t)gr * N + col0 + tx * 4] = o;
        }
    }
}

// ---------- edge scatter, layer 1: atomic max of 256-wide messages ----------
__global__ __launch_bounds__(256) void scatter_max(
    const float* __restrict__ xw, unsigned* __restrict__ agg,
    const int* __restrict__ src, const int* __restrict__ dst,
    const int* __restrict__ etype, int rel)
{
    int e = blockIdx.x * 4 + (threadIdx.x >> 6);
    if (e >= NE) return;
    if (etype[e] != rel) return;
    int lane = threadIdx.x & 63;
    int s = src[e], d = dst[e];
    float4 v = *(const float4*)&xw[(size_t)s * D_HID + lane * 4];
    unsigned* ap = &agg[(size_t)d * D_HID + lane * 4];
    atomicMax(ap + 0, fenc(v.x));
    atomicMax(ap + 1, fenc(v.y));
    atomicMax(ap + 2, fenc(v.z));
    atomicMax(ap + 3, fenc(v.w));
}

// ---------- edge scatter, layer 2: atomic add of 64-wide messages ----------
__global__ __launch_bounds__(256) void scatter_add(
    const float* __restrict__ xw, float* __restrict__ agg,
    const int* __restrict__ src, const int* __restrict__ dst,
    const int* __restrict__ etype, int rel)
{
    int e = blockIdx.x * 4 + (threadIdx.x >> 6);
    if (e >= NE) return;
    if (etype[e] != rel) return;
    int lane = threadIdx.x & 63;
    float v = xw[(size_t)src[e] * D_OUT + lane];
    atomicAdd(&agg[(size_t)dst[e] * D_OUT + lane], v);
}

// ---------- epilogue 1: decode max-agg + root + bias -> LN -> ReLU ----------
__global__ __launch_bounds__(256) void ln_relu1(
    const unsigned* __restrict__ agg, const float* __restrict__ rootp,
    const float* __restrict__ bias, const float* __restrict__ g,
    const float* __restrict__ b, float* __restrict__ h)
{
    int n = blockIdx.x * 4 + (threadIdx.x >> 6);
    if (n >= NN) return;
    int lane = threadIdx.x & 63;
    float t[4]; float s = 0.f, s2 = 0.f;
    #pragma unroll
    for (int i = 0; i < 4; i++) {
        int c = lane + i * 64;
        float a = fdec(agg[(size_t)n * D_HID + c]);
        if (a == -INFINITY) a = 0.f;   // empty segment -> 0
        float v = a + rootp[(size_t)n * D_HID + c] + bias[c];
        t[i] = v; s += v; s2 += v * v;
    }
    #pragma unroll
    for (int m = 32; m >= 1; m >>= 1) {
        s  += __shfl_xor(s,  m, 64);
        s2 += __shfl_xor(s2, m, 64);
    }
    float mu = s * (1.f / D_HID);
    float var = s2 * (1.f / D_HID) - mu * mu;
    float rs = rsqrtf(var + LN_EPS);
    #pragma unroll
    for (int i = 0; i < 4; i++) {
        int c = lane + i * 64;
        float y = (t[i] - mu) * rs * g[c] + b[c];
        h[(size_t)n * D_HID + c] = fmaxf(y, 0.f);
    }
}

// ---------- epilogue 2: agg + root + bias -> LN -> log_softmax ----------
__global__ __launch_bounds__(256) void final_k(
    const float* __restrict__ agg2, const float* __restrict__ rootp,
    const float* __restrict__ bias, const float* __restrict__ g,
    const float* __restrict__ b, float* __restrict__ out)
{
    int n = blockIdx.x * 4 + (threadIdx.x >> 6);
    if (n >= NN) return;
    int lane = threadIdx.x & 63;
    float v = agg2[(size_t)n * D_OUT + lane] + rootp[(size_t)n * D_OUT + lane] + bias[lane];
    float s = v, s2 = v * v;
    #pragma unroll
    for (int m = 32; m >= 1; m >>= 1) {
        s  += __shfl_xor(s,  m, 64);
        s2 += __shfl_xor(s2, m, 64);
    }
    float mu = s * (1.f / D_OUT);
    float var = s2 * (1.f / D_OUT) - mu * mu;
    float y = (v - mu) * rsqrtf(var + LN_EPS) * g[lane] + b[lane];
    // log_softmax over the 64 features (one per lane)
    float mx = y;
    #pragma unroll
    for (int m = 32; m >= 1; m >>= 1) mx = fmaxf(mx, __shfl_xor(mx, m, 64));
    float ex = __expf(y - mx);
    float se = ex;
    #pragma unroll
    for (int m = 32; m >= 1; m >>= 1) se += __shfl_xor(se, m, 64);
    out[(size_t)n * D_OUT + lane] = y - mx - logf(se);
}

extern "C" void kernel_launch(void* const* d_in, const int* in_sizes, int n_in,
                              void* d_out, int out_size, void* d_ws, size_t ws_size,
                              hipStream_t stream)
{
    const float* x      = (const float*)d_in[0];
    const int*   eidx   = (const int*)  d_in[1];
    const int*   etype  = (const int*)  d_in[2];
    const float* bases1 = (const float*)d_in[3];
    const float* comp1  = (const float*)d_in[4];
    const float* root1  = (const float*)d_in[5];
    const float* bias1  = (const float*)d_in[6];
    const float* g1     = (const float*)d_in[7];
    const float* b1     = (const float*)d_in[8];
    const float* bases2 = (const float*)d_in[9];
    const float* comp2  = (const float*)d_in[10];
    const float* root2  = (const float*)d_in[11];
    const float* bias2  = (const float*)d_in[12];
    const float* g2     = (const float*)d_in[13];
    const float* b2     = (const float*)d_in[14];

    const int* src = eidx;
    const int* dst = eidx + NE;

    // workspace layout (floats): w1 | w2 | xw | agg1(u32) | h | agg2  ~= 69 MB
    float*    w1   = (float*)d_ws;
    float*    w2   = w1 + NREL * D_IN * D_HID;                // +294912
    float*    xw   = w2 + NREL * D_HID * D_OUT;               // +147456
    unsigned* agg1 = (unsigned*)(xw + (size_t)NN * D_HID);    // +5120000
    float*    h    = (float*)(agg1 + (size_t)NN * D_HID);     // +5120000
    float*    agg2 = h + (size_t)NN * D_HID;                  // +5120000, size 1280000

    const int SZW = NREL * D_IN * D_HID + NREL * D_HID * D_OUT;   // 442368
    compute_w<<<(SZW + 255) / 256, 256, 0, stream>>>(bases1, comp1, bases2, comp2, w1, w2);

    // ---- layer 1 ----
    fill_u32<<<(NN * D_HID + 255) / 256, 256, 0, stream>>>(agg1, ENC_NEGINF, NN * D_HID);
    for (int r = 0; r < NREL; r++) {
        gemm_f32<<<dim3(D_HID / 64, (NN + 63) / 64), 256, 0, stream>>>(
            x, w1 + (size_t)r * D_IN * D_HID, xw, NN, D_HID, D_IN);
        scatter_max<<<(NE + 3) / 4, 256, 0, stream>>>(xw, agg1, src, dst, etype, r);
    }
    gemm_f32<<<dim3(D_HID / 64, (NN + 63) / 64), 256, 0, stream>>>(x, root1, xw, NN, D_HID, D_IN);
    ln_relu1<<<(NN + 3) / 4, 256, 0, stream>>>(agg1, xw, bias1, g1, b1, h);

    // ---- layer 2 ----
    fill_u32<<<(NN * D_OUT + 255) / 256, 256, 0, stream>>>((unsigned*)agg2, 0u, NN * D_OUT);
    for (int r = 0; r < NREL; r++) {
        gemm_f32<<<dim3(D_OUT / 64, (NN + 63) / 64), 256, 0, stream>>>(
            h, w2 + (size_t)r * D_HID * D_OUT, xw, NN, D_OUT, D_HID);
        scatter_add<<<(NE + 3) / 4, 256, 0, stream>>>(xw, agg2, src, dst, etype, r);
    }
    gemm_f32<<<dim3(D_OUT / 64, (NN + 63) / 64), 256, 0, stream>>>(h, root2, xw, NN, D_OUT, D_HID);
    final_k<<<(NN + 3) / 4, 256, 0, stream>>>(agg2, xw, bias2, g2, b2, (float*)d_out);
}

// Round 2
// 348.821 us; speedup vs baseline: 4.7509x; 4.7509x over previous
//
#include <hip/hip_runtime.h>
#include <math.h>

#define NN 20000
#define NE 320000
#define NREL 9
#define NBASES 9
#define D_IN 128
#define D_HID 256
#define D_OUT 64
#define LN_EPS 1e-5f

#define N1 (NREL * D_HID + D_HID)   // 2560 = 9 relation blocks + root block
#define N2 (NREL * D_OUT + D_OUT)   // 640

typedef __attribute__((ext_vector_type(8))) short bf16x8;   // 8 bf16 = 4 VGPRs
typedef __attribute__((ext_vector_type(4))) float f32x4;

__device__ inline ushort f2b(float f) {            // fp32 -> bf16 RNE
    unsigned u = __float_as_uint(f);
    return (ushort)((u + 0x7FFFu + ((u >> 16) & 1u)) >> 16);
}
__device__ inline float b2f(ushort h) { return __uint_as_float(((unsigned)h) << 16); }

// ---------- weight prep: w1t[n][k] = (basis-combined W1 | root1)^T in bf16 ----------
__global__ __launch_bounds__(256) void wprep1(
    const float* __restrict__ bases1, const float* __restrict__ comp1,
    const float* __restrict__ root1, ushort* __restrict__ w1t)
{
    int tid = blockIdx.x * 256 + threadIdx.x;
    if (tid >= N1 * D_IN) return;
    int n = tid >> 7, k = tid & 127;
    float s;
    if (n < NREL * D_HID) {
        int r = n >> 8, o = n & 255;
        s = 0.f;
        #pragma unroll
        for (int b = 0; b < NBASES; b++)
            s += comp1[r * NBASES + b] * bases1[(b * D_IN + k) * D_HID + o];
    } else {
        int o = n - NREL * D_HID;
        s = root1[k * D_HID + o];
    }
    w1t[tid] = f2b(s);
}

__global__ __launch_bounds__(256) void wprep2(
    const float* __restrict__ bases2, const float* __restrict__ comp2,
    const float* __restrict__ root2, ushort* __restrict__ w2t)
{
    int tid = blockIdx.x * 256 + threadIdx.x;
    if (tid >= N2 * D_HID) return;
    int n = tid >> 8, k = tid & 255;
    float s;
    if (n < NREL * D_OUT) {
        int r = n >> 6, o = n & 63;
        s = 0.f;
        #pragma unroll
        for (int b = 0; b < NBASES; b++)
            s += comp2[r * NBASES + b] * bases2[(b * D_HID + k) * D_OUT + o];
    } else {
        int o = n - NREL * D_OUT;
        s = root2[k * D_OUT + o];
    }
    w2t[tid] = f2b(s);
}

__global__ __launch_bounds__(256) void cast_x(const float* __restrict__ x, ushort* __restrict__ xb, int n)
{
    int i = blockIdx.x * 256 + threadIdx.x;
    if (i < n) xb[i] = f2b(x[i]);
}

__global__ __launch_bounds__(256) void fill_i32(int* __restrict__ p, int v, int n)
{
    int i = blockIdx.x * 256 + threadIdx.x;
    if (i < n) p[i] = v;
}

// ---------- CSR build ----------
__global__ __launch_bounds__(256) void hist_dst(const int* __restrict__ dst, int* __restrict__ deg)
{
    int e = blockIdx.x * 256 + threadIdx.x;
    if (e < NE) atomicAdd(&deg[dst[e]], 1);
}

// single-block exclusive scan over NN bins; also writes offs[NN] and cursor copy
__global__ __launch_bounds__(256) void scan_excl(
    const int* __restrict__ deg, int* __restrict__ offs, int* __restrict__ cursor)
{
    __shared__ int wsum[4];
    __shared__ int carry_s;
    int tid = threadIdx.x, lane = tid & 63, w = tid >> 6;
    if (tid == 0) carry_s = 0;
    __syncthreads();
    for (int base = 0; base < NN; base += 256) {
        int i = base + tid;
        int v = (i < NN) ? deg[i] : 0;
        int x = v;
        #pragma unroll
        for (int d = 1; d < 64; d <<= 1) {
            int y = __shfl_up(x, d, 64);
            if (lane >= d) x += y;
        }
        if (lane == 63) wsum[w] = x;
        __syncthreads();
        int woff = 0;
        for (int j = 0; j < w; j++) woff += wsum[j];
        int excl = carry_s + woff + x - v;
        if (i < NN) { offs[i] = excl; cursor[i] = excl; }
        __syncthreads();
        if (tid == 255) carry_s += wsum[0] + wsum[1] + wsum[2] + wsum[3];
        __syncthreads();
    }
    if (threadIdx.x == 0) offs[NN] = carry_s;
}

__global__ __launch_bounds__(256) void scatter_ep(
    const int* __restrict__ src, const int* __restrict__ dst, const int* __restrict__ etype,
    int* __restrict__ cursor, int* __restrict__ ep)
{
    int e = blockIdx.x * 256 + threadIdx.x;
    if (e >= NE) return;
    int d = dst[e];
    int pos = atomicAdd(&cursor[d], 1);
    ep[pos] = src[e] | (etype[e] << 16);
}

// ---------- bf16 MFMA GEMM: C[M][N] = A[M][K] @ Bt[N][K]^T, bf16 in/out, fp32 acc ----------
// N % 128 == 0, K % 32 == 0. Block 256 thr = 4 waves in 2x2; each wave 64x64 via 4x4 MFMA 16x16x32.
// LDS fragment-order layout: frag slot (tile t, lane l) at ushort offset (t*64+l)*8 holds
// A[t*16 + (l&15)][kq*8 + j] with l = (m&15) + kq*16 -- exactly the MFMA A/B operand layout.
__global__ __launch_bounds__(256) void gemm_bf16(
    const ushort* __restrict__ A, const ushort* __restrict__ Bt, ushort* __restrict__ C,
    int M, int N, int K)
{
    __shared__ ushort As[128 * 32];
    __shared__ ushort Bs[128 * 32];

    int tid = threadIdx.x;
    int lane = tid & 63, w = tid >> 6;
    int row0 = blockIdx.y * 128, col0 = blockIdx.x * 128;

    f32x4 acc[4][4];
    #pragma unroll
    for (int mt = 0; mt < 4; mt++)
        #pragma unroll
        for (int nt = 0; nt < 4; nt++)
            acc[mt][nt] = (f32x4){0.f, 0.f, 0.f, 0.f};

    for (int k0 = 0; k0 < K; k0 += 32) {
        #pragma unroll
        for (int cc = 0; cc < 2; cc++) {
            int c = tid + cc * 256;           // 0..511
            int m = c >> 2, kq = c & 3;
            int off = ((m >> 4) * 64 + (m & 15) + kq * 16) * 8;
            bf16x8 va = {0, 0, 0, 0, 0, 0, 0, 0};
            int gm = row0 + m;
            if (gm < M) va = *(const bf16x8*)&A[(size_t)gm * K + k0 + kq * 8];
            *(bf16x8*)&As[off] = va;
            bf16x8 vb = *(const bf16x8*)&Bt[(size_t)(col0 + m) * K + k0 + kq * 8];
            *(bf16x8*)&Bs[off] = vb;
        }
        __syncthreads();

        int tA = (w >> 1) * 4, tB = (w & 1) * 4;
        bf16x8 af[4], bfr[4];
        #pragma unroll
        for (int i = 0; i < 4; i++) af[i]  = *(const bf16x8*)&As[((tA + i) * 64 + lane) * 8];
        #pragma unroll
        for (int i = 0; i < 4; i++) bfr[i] = *(const bf16x8*)&Bs[((tB + i) * 64 + lane) * 8];

        #pragma unroll
        for (int mt = 0; mt < 4; mt++)
            #pragma unroll
            for (int nt = 0; nt < 4; nt++)
                acc[mt][nt] = __builtin_amdgcn_mfma_f32_16x16x32_bf16(af[mt], bfr[nt], acc[mt][nt], 0, 0, 0);
        __syncthreads();
    }

    int q = lane >> 4, cn = lane & 15;
    #pragma unroll
    for (int mt = 0; mt < 4; mt++) {
        #pragma unroll
        for (int i = 0; i < 4; i++) {
            int gr = row0 + (w >> 1) * 64 + mt * 16 + q * 4 + i;
            if (gr < M) {
                #pragma unroll
                for (int nt = 0; nt < 4; nt++) {
                    int gc = col0 + (w & 1) * 64 + nt * 16 + cn;
                    C[(size_t)gr * N + gc] = f2b(acc[mt][nt][i]);
                }
            }
        }
    }
}

// ---------- gather1: max over in-edges + root + bias -> LN -> ReLU -> h (bf16) ----------
__global__ __launch_bounds__(256) void gather1(
    const ushort* __restrict__ xw1, const int* __restrict__ offs, const int* __restrict__ ep,
    const float* __restrict__ bias, const float* __restrict__ g, const float* __restrict__ b,
    ushort* __restrict__ h)
{
    int n = blockIdx.x * 4 + (threadIdx.x >> 6);
    if (n >= NN) return;
    int lane = threadIdx.x & 63;
    int e0 = offs[n], e1 = offs[n + 1];

    float m0 = -INFINITY, m1 = -INFINITY, m2 = -INFINITY, m3 = -INFINITY;
    for (int e = e0; e < e1; e++) {
        int p = ep[e];
        int src = p & 0xFFFF, rel = p >> 16;
        ushort4 v = *(const ushort4*)&xw1[(size_t)src * N1 + rel * D_HID + lane * 4];
        m0 = fmaxf(m0, b2f(v.x)); m1 = fmaxf(m1, b2f(v.y));
        m2 = fmaxf(m2, b2f(v.z)); m3 = fmaxf(m3, b2f(v.w));
    }
    if (e1 == e0) { m0 = m1 = m2 = m3 = 0.f; }   // empty segment -> 0

    ushort4 rt = *(const ushort4*)&xw1[(size_t)n * N1 + NREL * D_HID + lane * 4];
    int c = lane * 4;
    float t0 = m0 + b2f(rt.x) + bias[c + 0];
    float t1 = m1 + b2f(rt.y) + bias[c + 1];
    float t2 = m2 + b2f(rt.z) + bias[c + 2];
    float t3 = m3 + b2f(rt.w) + bias[c + 3];

    float s = t0 + t1 + t2 + t3;
    float s2 = t0 * t0 + t1 * t1 + t2 * t2 + t3 * t3;
    #pragma unroll
    for (int m = 32; m >= 1; m >>= 1) {
        s  += __shfl_xor(s,  m, 64);
        s2 += __shfl_xor(s2, m, 64);
    }
    float mu = s * (1.f / D_HID);
    float var = s2 * (1.f / D_HID) - mu * mu;
    float rs = rsqrtf(var + LN_EPS);

    ushort4 o;
    o.x = f2b(fmaxf((t0 - mu) * rs * g[c + 0] + b[c + 0], 0.f));
    o.y = f2b(fmaxf((t1 - mu) * rs * g[c + 1] + b[c + 1], 0.f));
    o.z = f2b(fmaxf((t2 - mu) * rs * g[c + 2] + b[c + 2], 0.f));
    o.w = f2b(fmaxf((t3 - mu) * rs * g[c + 3] + b[c + 3], 0.f));
    *(ushort4*)&h[(size_t)n * D_HID + c] = o;
}

// ---------- gather2: sum over in-edges + root + bias -> LN -> log_softmax -> out (fp32) ----------
__global__ __launch_bounds__(256) void gather2(
    const ushort* __restrict__ xw2, const int* __restrict__ offs, const int* __restrict__ ep,
    const float* __restrict__ bias, const float* __restrict__ g, const float* __restrict__ b,
    float* __restrict__ out)
{
    int n = blockIdx.x * 4 + (threadIdx.x >> 6);
    if (n >= NN) return;
    int lane = threadIdx.x & 63;
    int e0 = offs[n], e1 = offs[n + 1];

    float s = 0.f;
    for (int e = e0; e < e1; e++) {
        int p = ep[e];
        int src = p & 0xFFFF, rel = p >> 16;
        s += b2f(xw2[(size_t)src * N2 + rel * D_OUT + lane]);
    }
    float v = s + b2f(xw2[(size_t)n * N2 + NREL * D_OUT + lane]) + bias[lane];

    float sm = v, s2 = v * v;
    #pragma unroll
    for (int m = 32; m >= 1; m >>= 1) {
        sm += __shfl_xor(sm, m, 64);
        s2 += __shfl_xor(s2, m, 64);
    }
    float mu = sm * (1.f / D_OUT);
    float var = s2 * (1.f / D_OUT) - mu * mu;
    float y = (v - mu) * rsqrtf(var + LN_EPS) * g[lane] + b[lane];

    float mx = y;
    #pragma unroll
    for (int m = 32; m >= 1; m >>= 1) mx = fmaxf(mx, __shfl_xor(mx, m, 64));
    float ex = __expf(y - mx);
    float se = ex;
    #pragma unroll
    for (int m = 32; m >= 1; m >>= 1) se += __shfl_xor(se, m, 64);
    out[(size_t)n * D_OUT + lane] = y - mx - logf(se);
}

extern "C" void kernel_launch(void* const* d_in, const int* in_sizes, int n_in,
                              void* d_out, int out_size, void* d_ws, size_t ws_size,
                              hipStream_t stream)
{
    const float* x      = (const float*)d_in[0];
    const int*   eidx   = (const int*)  d_in[1];
    const int*   etype  = (const int*)  d_in[2];
    const float* bases1 = (const float*)d_in[3];
    const float* comp1  = (const float*)d_in[4];
    const float* root1  = (const float*)d_in[5];
    const float* bias1  = (const float*)d_in[6];
    const float* g1     = (const float*)d_in[7];
    const float* b1     = (const float*)d_in[8];
    const float* bases2 = (const float*)d_in[9];
    const float* comp2  = (const float*)d_in[10];
    const float* root2  = (const float*)d_in[11];
    const float* bias2  = (const float*)d_in[12];
    const float* g2     = (const float*)d_in[13];
    const float* b2     = (const float*)d_in[14];

    const int* src = eidx;
    const int* dst = eidx + NE;

    // workspace carve-up (256B aligned); total ~146 MB
    char* p = (char*)d_ws;
    auto alloc = [&](size_t bytes) -> char* {
        char* r = p;
        p += (bytes + 255) & ~(size_t)255;
        return r;
    };
    ushort* xbf    = (ushort*)alloc((size_t)NN * D_IN * 2);      // 5.1 MB
    ushort* w1t    = (ushort*)alloc((size_t)N1 * D_IN * 2);      // 0.66 MB
    ushort* w2t    = (ushort*)alloc((size_t)N2 * D_HID * 2);     // 0.33 MB
    ushort* xw1    = (ushort*)alloc((size_t)NN * N1 * 2);        // 102.4 MB
    ushort* xw2    = (ushort*)alloc((size_t)NN * N2 * 2);        // 25.6 MB
    ushort* h      = (ushort*)alloc((size_t)NN * D_HID * 2);     // 10.2 MB
    int*    deg    = (int*)   alloc((size_t)(NN) * 4);
    int*    offs   = (int*)   alloc((size_t)(NN + 1) * 4);
    int*    cursor = (int*)   alloc((size_t)NN * 4);
    int*    ep     = (int*)   alloc((size_t)NE * 4);             // 1.3 MB

    // weights + input cast
    wprep1<<<(N1 * D_IN + 255) / 256, 256, 0, stream>>>(bases1, comp1, root1, w1t);
    wprep2<<<(N2 * D_HID + 255) / 256, 256, 0, stream>>>(bases2, comp2, root2, w2t);
    cast_x<<<(NN * D_IN + 255) / 256, 256, 0, stream>>>(x, xbf, NN * D_IN);

    // CSR by dst
    fill_i32<<<(NN + 255) / 256, 256, 0, stream>>>(deg, 0, NN);
    hist_dst<<<(NE + 255) / 256, 256, 0, stream>>>(dst, deg);
    scan_excl<<<1, 256, 0, stream>>>(deg, offs, cursor);
    scatter_ep<<<(NE + 255) / 256, 256, 0, stream>>>(src, dst, etype, cursor, ep);

    // layer 1: one fused GEMM (9 relations + root), then gather-max + LN + ReLU
    gemm_bf16<<<dim3(N1 / 128, (NN + 127) / 128), 256, 0, stream>>>(xbf, w1t, xw1, NN, N1, D_IN);
    gather1<<<(NN + 3) / 4, 256, 0, stream>>>(xw1, offs, ep, bias1, g1, b1, h);

    // layer 2: one fused GEMM, then gather-sum + LN + log_softmax
    gemm_bf16<<<dim3(N2 / 128, (NN + 127) / 128), 256, 0, stream>>>(h, w2t, xw2, NN, N2, D_HID);
    gather2<<<(NN + 3) / 4, 256, 0, stream>>>(xw2, offs, ep, bias2, g2, b2, (float*)d_out);
}

// Round 3
// 287.504 us; speedup vs baseline: 5.7641x; 1.2133x over previous
//
#include <hip/hip_runtime.h>
#include <math.h>

#define NN 20000
#define NE 320000
#define NREL 9
#define NBASES 9
#define D_IN 128
#define D_HID 256
#define D_OUT 64
#define LN_EPS 1e-5f

#define N1 (NREL * D_HID + D_HID)   // 2560 = 9 relation blocks + root block
#define N2 (NREL * D_OUT + D_OUT)   // 640
#define NBLK ((NN + 255) / 256)     // 79 scan blocks

typedef __attribute__((ext_vector_type(8))) short bf16x8;   // 8 bf16 = 4 VGPRs
typedef __attribute__((ext_vector_type(4))) float f32x4;

__device__ inline ushort f2b(float f) {            // fp32 -> bf16 RNE
    unsigned u = __float_as_uint(f);
    return (ushort)((u + 0x7FFFu + ((u >> 16) & 1u)) >> 16);
}
__device__ inline float b2f(ushort h) { return __uint_as_float(((unsigned)h) << 16); }

// ---------- fused prep: w1t, w2t (basis-combined, transposed, bf16) + x cast ----------
__global__ __launch_bounds__(256) void prep_all(
    const float* __restrict__ bases1, const float* __restrict__ comp1, const float* __restrict__ root1,
    const float* __restrict__ bases2, const float* __restrict__ comp2, const float* __restrict__ root2,
    const float* __restrict__ x,
    ushort* __restrict__ w1t, ushort* __restrict__ w2t, ushort* __restrict__ xbf)
{
    const int SZ1 = N1 * D_IN;     // 327680
    const int SZ2 = N2 * D_HID;    // 163840
    const int SZX = NN * D_IN;     // 2560000
    int tid = blockIdx.x * 256 + threadIdx.x;
    if (tid < SZ1) {
        int n = tid >> 7, k = tid & 127;
        float s;
        if (n < NREL * D_HID) {
            int r = n >> 8, o = n & 255;
            s = 0.f;
            #pragma unroll
            for (int b = 0; b < NBASES; b++)
                s += comp1[r * NBASES + b] * bases1[(b * D_IN + k) * D_HID + o];
        } else {
            s = root1[k * D_HID + (n - NREL * D_HID)];
        }
        w1t[tid] = f2b(s);
    } else if (tid < SZ1 + SZ2) {
        int j = tid - SZ1;
        int n = j >> 8, k = j & 255;
        float s;
        if (n < NREL * D_OUT) {
            int r = n >> 6, o = n & 63;
            s = 0.f;
            #pragma unroll
            for (int b = 0; b < NBASES; b++)
                s += comp2[r * NBASES + b] * bases2[(b * D_HID + k) * D_OUT + o];
        } else {
            s = root2[k * D_OUT + (n - NREL * D_OUT)];
        }
        w2t[j] = f2b(s);
    } else if (tid < SZ1 + SZ2 + SZX) {
        int j = tid - SZ1 - SZ2;
        xbf[j] = f2b(x[j]);
    }
}

// ---------- CSR build ----------
__global__ __launch_bounds__(256) void hist_dst(const int* __restrict__ dst, int* __restrict__ deg)
{
    int e = blockIdx.x * 256 + threadIdx.x;
    if (e < NE) atomicAdd(&deg[dst[e]], 1);
}

// stage 1: per-block (256-elem) exclusive scan; emit block sums
__global__ __launch_bounds__(256) void scan_blk(
    const int* __restrict__ deg, int* __restrict__ local, int* __restrict__ bsum)
{
    __shared__ int wsum[4];
    int tid = threadIdx.x, lane = tid & 63, w = tid >> 6;
    int i = blockIdx.x * 256 + tid;
    int v = (i < NN) ? deg[i] : 0;
    int x = v;
    #pragma unroll
    for (int d = 1; d < 64; d <<= 1) {
        int y = __shfl_up(x, d, 64);
        if (lane >= d) x += y;
    }
    if (lane == 63) wsum[w] = x;
    __syncthreads();
    int woff = 0;
    for (int j = 0; j < w; j++) woff += wsum[j];
    if (i < NN) local[i] = woff + x - v;
    if (tid == 255) bsum[blockIdx.x] = woff + x;
}

// stage 2: one wave scans the NBLK block sums (exclusive)
__global__ __launch_bounds__(64) void scan_top(const int* __restrict__ bsum, int* __restrict__ boff)
{
    int lane = threadIdx.x;
    int carry = 0;
    for (int base = 0; base < NBLK; base += 64) {
        int i = base + lane;
        int v = (i < NBLK) ? bsum[i] : 0;
        int x = v;
        #pragma unroll
        for (int d = 1; d < 64; d <<= 1) {
            int y = __shfl_up(x, d, 64);
            if (lane >= d) x += y;
        }
        if (i < NBLK) boff[i] = carry + x - v;
        carry += __shfl(x, 63, 64);
    }
}

// stage 3: finalize offs + cursor copy; offs[NN] == NE by construction
__global__ __launch_bounds__(256) void scan_fin(
    const int* __restrict__ local, const int* __restrict__ boff,
    int* __restrict__ offs, int* __restrict__ cursor)
{
    int i = blockIdx.x * 256 + threadIdx.x;
    if (i < NN) {
        int o = local[i] + boff[i >> 8];
        offs[i] = o;
        cursor[i] = o;
    }
    if (i == NN) offs[NN] = NE;
}

__global__ __launch_bounds__(256) void scatter_ep(
    const int* __restrict__ src, const int* __restrict__ dst, const int* __restrict__ etype,
    int* __restrict__ cursor, int* __restrict__ ep)
{
    int e = blockIdx.x * 256 + threadIdx.x;
    if (e >= NE) return;
    int d = dst[e];
    int pos = atomicAdd(&cursor[d], 1);
    ep[pos] = src[e] | (etype[e] << 16);
}

// ---------- bf16 MFMA GEMM: C[M][N] = A[M][K] @ Bt[N][K]^T, bf16 in/out, fp32 acc ----------
// Block 256 thr = 4 waves in 2x2; each wave 64x64 via 4x4 MFMA 16x16x32.
// LDS fragment-order layout: frag slot (tile t, lane l) at ushort offset (t*64+l)*8 holds
// A[t*16 + (l&15)][kq*8 + j] with l = (m&15) + kq*16 -- exactly the MFMA A/B operand layout.
__global__ __launch_bounds__(256) void gemm_bf16(
    const ushort* __restrict__ A, const ushort* __restrict__ Bt, ushort* __restrict__ C,
    int M, int N, int K)
{
    __shared__ ushort As[128 * 32];
    __shared__ ushort Bs[128 * 32];

    int tid = threadIdx.x;
    int lane = tid & 63, w = tid >> 6;
    int row0 = blockIdx.y * 128, col0 = blockIdx.x * 128;

    f32x4 acc[4][4];
    #pragma unroll
    for (int mt = 0; mt < 4; mt++)
        #pragma unroll
        for (int nt = 0; nt < 4; nt++)
            acc[mt][nt] = (f32x4){0.f, 0.f, 0.f, 0.f};

    for (int k0 = 0; k0 < K; k0 += 32) {
        #pragma unroll
        for (int cc = 0; cc < 2; cc++) {
            int c = tid + cc * 256;           // 0..511
            int m = c >> 2, kq = c & 3;
            int off = ((m >> 4) * 64 + (m & 15) + kq * 16) * 8;
            bf16x8 va = {0, 0, 0, 0, 0, 0, 0, 0};
            int gm = row0 + m;
            if (gm < M) va = *(const bf16x8*)&A[(size_t)gm * K + k0 + kq * 8];
            *(bf16x8*)&As[off] = va;
            bf16x8 vb = *(const bf16x8*)&Bt[(size_t)(col0 + m) * K + k0 + kq * 8];
            *(bf16x8*)&Bs[off] = vb;
        }
        __syncthreads();

        int tA = (w >> 1) * 4, tB = (w & 1) * 4;
        bf16x8 af[4], bfr[4];
        #pragma unroll
        for (int i = 0; i < 4; i++) af[i]  = *(const bf16x8*)&As[((tA + i) * 64 + lane) * 8];
        #pragma unroll
        for (int i = 0; i < 4; i++) bfr[i] = *(const bf16x8*)&Bs[((tB + i) * 64 + lane) * 8];

        #pragma unroll
        for (int mt = 0; mt < 4; mt++)
            #pragma unroll
            for (int nt = 0; nt < 4; nt++)
                acc[mt][nt] = __builtin_amdgcn_mfma_f32_16x16x32_bf16(af[mt], bfr[nt], acc[mt][nt], 0, 0, 0);
        __syncthreads();
    }

    int q = lane >> 4, cn = lane & 15;
    #pragma unroll
    for (int mt = 0; mt < 4; mt++) {
        #pragma unroll
        for (int i = 0; i < 4; i++) {
            int gr = row0 + (w >> 1) * 64 + mt * 16 + q * 4 + i;
            if (gr < M) {
                #pragma unroll
                for (int nt = 0; nt < 4; nt++) {
                    int gc = col0 + (w & 1) * 64 + nt * 16 + cn;
                    C[(size_t)gr * N + gc] = f2b(acc[mt][nt][i]);
                }
            }
        }
    }
}

// ---------- gather1: max over in-edges + root + bias -> LN -> ReLU -> h (bf16) ----------
__global__ __launch_bounds__(256) void gather1(
    const ushort* __restrict__ xw1, const int* __restrict__ offs, const int* __restrict__ ep,
    const float* __restrict__ bias, const float* __restrict__ g, const float* __restrict__ b,
    ushort* __restrict__ h)
{
    int n = blockIdx.x * 4 + (threadIdx.x >> 6);
    if (n >= NN) return;
    int lane = threadIdx.x & 63;
    int e0 = offs[n], e1 = offs[n + 1];

    float m0 = -INFINITY, m1 = -INFINITY, m2 = -INFINITY, m3 = -INFINITY;
    for (int e = e0; e < e1; e++) {
        int p = ep[e];
        int src = p & 0xFFFF, rel = p >> 16;
        ushort4 v = *(const ushort4*)&xw1[(size_t)src * N1 + rel * D_HID + lane * 4];
        m0 = fmaxf(m0, b2f(v.x)); m1 = fmaxf(m1, b2f(v.y));
        m2 = fmaxf(m2, b2f(v.z)); m3 = fmaxf(m3, b2f(v.w));
    }
    if (e1 == e0) { m0 = m1 = m2 = m3 = 0.f; }   // empty segment -> 0

    ushort4 rt = *(const ushort4*)&xw1[(size_t)n * N1 + NREL * D_HID + lane * 4];
    int c = lane * 4;
    float t0 = m0 + b2f(rt.x) + bias[c + 0];
    float t1 = m1 + b2f(rt.y) + bias[c + 1];
    float t2 = m2 + b2f(rt.z) + bias[c + 2];
    float t3 = m3 + b2f(rt.w) + bias[c + 3];

    float s = t0 + t1 + t2 + t3;
    float s2 = t0 * t0 + t1 * t1 + t2 * t2 + t3 * t3;
    #pragma unroll
    for (int m = 32; m >= 1; m >>= 1) {
        s  += __shfl_xor(s,  m, 64);
        s2 += __shfl_xor(s2, m, 64);
    }
    float mu = s * (1.f / D_HID);
    float var = s2 * (1.f / D_HID) - mu * mu;
    float rs = rsqrtf(var + LN_EPS);

    ushort4 o;
    o.x = f2b(fmaxf((t0 - mu) * rs * g[c + 0] + b[c + 0], 0.f));
    o.y = f2b(fmaxf((t1 - mu) * rs * g[c + 1] + b[c + 1], 0.f));
    o.z = f2b(fmaxf((t2 - mu) * rs * g[c + 2] + b[c + 2], 0.f));
    o.w = f2b(fmaxf((t3 - mu) * rs * g[c + 3] + b[c + 3], 0.f));
    *(ushort4*)&h[(size_t)n * D_HID + c] = o;
}

// ---------- gather2: sum over in-edges + root + bias -> LN -> log_softmax -> out (fp32) ----------
__global__ __launch_bounds__(256) void gather2(
    const ushort* __restrict__ xw2, const int* __restrict__ offs, const int* __restrict__ ep,
    const float* __restrict__ bias, const float* __restrict__ g, const float* __restrict__ b,
    float* __restrict__ out)
{
    int n = blockIdx.x * 4 + (threadIdx.x >> 6);
    if (n >= NN) return;
    int lane = threadIdx.x & 63;
    int e0 = offs[n], e1 = offs[n + 1];

    float s = 0.f;
    for (int e = e0; e < e1; e++) {
        int p = ep[e];
        int src = p & 0xFFFF, rel = p >> 16;
        s += b2f(xw2[(size_t)src * N2 + rel * D_OUT + lane]);
    }
    float v = s + b2f(xw2[(size_t)n * N2 + NREL * D_OUT + lane]) + bias[lane];

    float sm = v, s2 = v * v;
    #pragma unroll
    for (int m = 32; m >= 1; m >>= 1) {
        sm += __shfl_xor(sm, m, 64);
        s2 += __shfl_xor(s2, m, 64);
    }
    float mu = sm * (1.f / D_OUT);
    float var = s2 * (1.f / D_OUT) - mu * mu;
    float y = (v - mu) * rsqrtf(var + LN_EPS) * g[lane] + b[lane];

    float mx = y;
    #pragma unroll
    for (int m = 32; m >= 1; m >>= 1) mx = fmaxf(mx, __shfl_xor(mx, m, 64));
    float ex = __expf(y - mx);
    float se = ex;
    #pragma unroll
    for (int m = 32; m >= 1; m >>= 1) se += __shfl_xor(se, m, 64);
    out[(size_t)n * D_OUT + lane] = y - mx - logf(se);
}

extern "C" void kernel_launch(void* const* d_in, const int* in_sizes, int n_in,
                              void* d_out, int out_size, void* d_ws, size_t ws_size,
                              hipStream_t stream)
{
    const float* x      = (const float*)d_in[0];
    const int*   eidx   = (const int*)  d_in[1];
    const int*   etype  = (const int*)  d_in[2];
    const float* bases1 = (const float*)d_in[3];
    const float* comp1  = (const float*)d_in[4];
    const float* root1  = (const float*)d_in[5];
    const float* bias1  = (const float*)d_in[6];
    const float* g1     = (const float*)d_in[7];
    const float* b1     = (const float*)d_in[8];
    const float* bases2 = (const float*)d_in[9];
    const float* comp2  = (const float*)d_in[10];
    const float* root2  = (const float*)d_in[11];
    const float* bias2  = (const float*)d_in[12];
    const float* g2     = (const float*)d_in[13];
    const float* b2     = (const float*)d_in[14];

    const int* src = eidx;
    const int* dst = eidx + NE;

    // workspace carve-up (256B aligned); total ~146 MB
    char* p = (char*)d_ws;
    auto alloc = [&](size_t bytes) -> char* {
        char* r = p;
        p += (bytes + 255) & ~(size_t)255;
        return r;
    };
    ushort* xbf    = (ushort*)alloc((size_t)NN * D_IN * 2);      // 5.1 MB
    ushort* w1t    = (ushort*)alloc((size_t)N1 * D_IN * 2);      // 0.66 MB
    ushort* w2t    = (ushort*)alloc((size_t)N2 * D_HID * 2);     // 0.33 MB
    ushort* xw1    = (ushort*)alloc((size_t)NN * N1 * 2);        // 102.4 MB
    ushort* xw2    = (ushort*)alloc((size_t)NN * N2 * 2);        // 25.6 MB
    ushort* h      = (ushort*)alloc((size_t)NN * D_HID * 2);     // 10.2 MB
    int*    deg    = (int*)   alloc((size_t)NN * 4);
    int*    local  = (int*)   alloc((size_t)NN * 4);
    int*    bsum   = (int*)   alloc((size_t)NBLK * 4);
    int*    boff   = (int*)   alloc((size_t)NBLK * 4);
    int*    offs   = (int*)   alloc((size_t)(NN + 1) * 4);
    int*    cursor = (int*)   alloc((size_t)NN * 4);
    int*    ep     = (int*)   alloc((size_t)NE * 4);             // 1.3 MB

    // prep (weights + x cast) and CSR build
    const int SZP = N1 * D_IN + N2 * D_HID + NN * D_IN;
    prep_all<<<(SZP + 255) / 256, 256, 0, stream>>>(
        bases1, comp1, root1, bases2, comp2, root2, x, w1t, w2t, xbf);

    hipMemsetAsync(deg, 0, (size_t)NN * 4, stream);
    hist_dst<<<(NE + 255) / 256, 256, 0, stream>>>(dst, deg);
    scan_blk<<<NBLK, 256, 0, stream>>>(deg, local, bsum);
    scan_top<<<1, 64, 0, stream>>>(bsum, boff);
    scan_fin<<<NBLK, 256, 0, stream>>>(local, boff, offs, cursor);
    scatter_ep<<<(NE + 255) / 256, 256, 0, stream>>>(src, dst, etype, cursor, ep);

    // layer 1: one fused GEMM (9 relations + root), then gather-max + LN + ReLU
    gemm_bf16<<<dim3(N1 / 128, (NN + 127) / 128), 256, 0, stream>>>(xbf, w1t, xw1, NN, N1, D_IN);
    gather1<<<(NN + 3) / 4, 256, 0, stream>>>(xw1, offs, ep, bias1, g1, b1, h);

    // layer 2: one fused GEMM, then gather-sum + LN + log_softmax
    gemm_bf16<<<dim3(N2 / 128, (NN + 127) / 128), 256, 0, stream>>>(h, w2t, xw2, NN, N2, D_HID);
    gather2<<<(NN + 3) / 4, 256, 0, stream>>>(xw2, offs, ep, bias2, g2, b2, (float*)d_out);
}

// Round 4
// 251.645 us; speedup vs baseline: 6.5855x; 1.1425x over previous
//
#include <hip/hip_runtime.h>
#include <math.h>

#define NN 20000
#define NE 320000
#define NREL 9
#define NBASES 9
#define D_IN 128
#define D_HID 256
#define D_OUT 64
#define LN_EPS 1e-5f

#define N1 (NREL * D_HID + D_HID)   // 2560 = 9 relation blocks + root block
#define N2 (NREL * D_OUT + D_OUT)   // 640
#define NBLK ((NN + 255) / 256)     // 79 scan blocks

typedef __attribute__((ext_vector_type(8))) short bf16x8;   // 8 bf16 = 4 VGPRs
typedef __attribute__((ext_vector_type(4))) float f32x4;

__device__ inline ushort f2b(float f) {            // fp32 -> bf16 RNE
    unsigned u = __float_as_uint(f);
    return (ushort)((u + 0x7FFFu + ((u >> 16) & 1u)) >> 16);
}
__device__ inline float b2f(ushort h) { return __uint_as_float(((unsigned)h) << 16); }

// ---------- fused prep: w1t, w2t (basis-combined, transposed, bf16) + x cast ----------
__global__ __launch_bounds__(256) void prep_all(
    const float* __restrict__ bases1, const float* __restrict__ comp1, const float* __restrict__ root1,
    const float* __restrict__ bases2, const float* __restrict__ comp2, const float* __restrict__ root2,
    const float* __restrict__ x,
    ushort* __restrict__ w1t, ushort* __restrict__ w2t, ushort* __restrict__ xbf)
{
    const int SZ1 = N1 * D_IN;     // 327680
    const int SZ2 = N2 * D_HID;    // 163840
    const int SZX = NN * D_IN;     // 2560000
    int tid = blockIdx.x * 256 + threadIdx.x;
    if (tid < SZ1) {
        int n = tid >> 7, k = tid & 127;
        float s;
        if (n < NREL * D_HID) {
            int r = n >> 8, o = n & 255;
            s = 0.f;
            #pragma unroll
            for (int b = 0; b < NBASES; b++)
                s += comp1[r * NBASES + b] * bases1[(b * D_IN + k) * D_HID + o];
        } else {
            s = root1[k * D_HID + (n - NREL * D_HID)];
        }
        w1t[tid] = f2b(s);
    } else if (tid < SZ1 + SZ2) {
        int j = tid - SZ1;
        int n = j >> 8, k = j & 255;
        float s;
        if (n < NREL * D_OUT) {
            int r = n >> 6, o = n & 63;
            s = 0.f;
            #pragma unroll
            for (int b = 0; b < NBASES; b++)
                s += comp2[r * NBASES + b] * bases2[(b * D_HID + k) * D_OUT + o];
        } else {
            s = root2[k * D_OUT + (n - NREL * D_OUT)];
        }
        w2t[j] = f2b(s);
    } else if (tid < SZ1 + SZ2 + SZX) {
        int j = tid - SZ1 - SZ2;
        xbf[j] = f2b(x[j]);
    }
}

// ---------- CSR build ----------
__global__ __launch_bounds__(256) void hist_dst(const int* __restrict__ dst, int* __restrict__ deg)
{
    int e = blockIdx.x * 256 + threadIdx.x;
    if (e < NE) atomicAdd(&deg[dst[e]], 1);
}

// stage 1: per-block (256-elem) exclusive scan; emit block sums
__global__ __launch_bounds__(256) void scan_blk(
    const int* __restrict__ deg, int* __restrict__ local, int* __restrict__ bsum)
{
    __shared__ int wsum[4];
    int tid = threadIdx.x, lane = tid & 63, w = tid >> 6;
    int i = blockIdx.x * 256 + tid;
    int v = (i < NN) ? deg[i] : 0;
    int x = v;
    #pragma unroll
    for (int d = 1; d < 64; d <<= 1) {
        int y = __shfl_up(x, d, 64);
        if (lane >= d) x += y;
    }
    if (lane == 63) wsum[w] = x;
    __syncthreads();
    int woff = 0;
    for (int j = 0; j < w; j++) woff += wsum[j];
    if (i < NN) local[i] = woff + x - v;
    if (tid == 255) bsum[blockIdx.x] = woff + x;
}

// stage 2: one wave scans the NBLK block sums (exclusive)
__global__ __launch_bounds__(64) void scan_top(const int* __restrict__ bsum, int* __restrict__ boff)
{
    int lane = threadIdx.x;
    int carry = 0;
    for (int base = 0; base < NBLK; base += 64) {
        int i = base + lane;
        int v = (i < NBLK) ? bsum[i] : 0;
        int x = v;
        #pragma unroll
        for (int d = 1; d < 64; d <<= 1) {
            int y = __shfl_up(x, d, 64);
            if (lane >= d) x += y;
        }
        if (i < NBLK) boff[i] = carry + x - v;
        carry += __shfl(x, 63, 64);
    }
}

// stage 3: finalize offs + cursor copy; offs[NN] == NE by construction
__global__ __launch_bounds__(256) void scan_fin(
    const int* __restrict__ local, const int* __restrict__ boff,
    int* __restrict__ offs, int* __restrict__ cursor)
{
    int i = blockIdx.x * 256 + threadIdx.x;
    if (i < NN) {
        int o = local[i] + boff[i >> 8];
        offs[i] = o;
        cursor[i] = o;
    }
    if (i == NN) offs[NN] = NE;
}

// writes per-layer precomputed element offsets: ep1 = src*N1 + rel*D_HID, ep2 = src*N2 + rel*D_OUT
__global__ __launch_bounds__(256) void scatter_ep(
    const int* __restrict__ src, const int* __restrict__ dst, const int* __restrict__ etype,
    int* __restrict__ cursor, int* __restrict__ ep1, int* __restrict__ ep2)
{
    int e = blockIdx.x * 256 + threadIdx.x;
    if (e >= NE) return;
    int d = dst[e];
    int s = src[e], r = etype[e];
    int pos = atomicAdd(&cursor[d], 1);
    ep1[pos] = s * N1 + r * D_HID;
    ep2[pos] = s * N2 + r * D_OUT;
}

// ---------- bf16 MFMA GEMM: C[M][N] = A[M][K] @ Bt[N][K]^T, bf16 in/out, fp32 acc ----------
__global__ __launch_bounds__(256) void gemm_bf16(
    const ushort* __restrict__ A, const ushort* __restrict__ Bt, ushort* __restrict__ C,
    int M, int N, int K)
{
    __shared__ ushort As[128 * 32];
    __shared__ ushort Bs[128 * 32];

    int tid = threadIdx.x;
    int lane = tid & 63, w = tid >> 6;
    int row0 = blockIdx.y * 128, col0 = blockIdx.x * 128;

    f32x4 acc[4][4];
    #pragma unroll
    for (int mt = 0; mt < 4; mt++)
        #pragma unroll
        for (int nt = 0; nt < 4; nt++)
            acc[mt][nt] = (f32x4){0.f, 0.f, 0.f, 0.f};

    for (int k0 = 0; k0 < K; k0 += 32) {
        #pragma unroll
        for (int cc = 0; cc < 2; cc++) {
            int c = tid + cc * 256;           // 0..511
            int m = c >> 2, kq = c & 3;
            int off = ((m >> 4) * 64 + (m & 15) + kq * 16) * 8;
            bf16x8 va = {0, 0, 0, 0, 0, 0, 0, 0};
            int gm = row0 + m;
            if (gm < M) va = *(const bf16x8*)&A[(size_t)gm * K + k0 + kq * 8];
            *(bf16x8*)&As[off] = va;
            bf16x8 vb = *(const bf16x8*)&Bt[(size_t)(col0 + m) * K + k0 + kq * 8];
            *(bf16x8*)&Bs[off] = vb;
        }
        __syncthreads();

        int tA = (w >> 1) * 4, tB = (w & 1) * 4;
        bf16x8 af[4], bfr[4];
        #pragma unroll
        for (int i = 0; i < 4; i++) af[i]  = *(const bf16x8*)&As[((tA + i) * 64 + lane) * 8];
        #pragma unroll
        for (int i = 0; i < 4; i++) bfr[i] = *(const bf16x8*)&Bs[((tB + i) * 64 + lane) * 8];

        #pragma unroll
        for (int mt = 0; mt < 4; mt++)
            #pragma unroll
            for (int nt = 0; nt < 4; nt++)
                acc[mt][nt] = __builtin_amdgcn_mfma_f32_16x16x32_bf16(af[mt], bfr[nt], acc[mt][nt], 0, 0, 0);
        __syncthreads();
    }

    int q = lane >> 4, cn = lane & 15;
    #pragma unroll
    for (int mt = 0; mt < 4; mt++) {
        #pragma unroll
        for (int i = 0; i < 4; i++) {
            int gr = row0 + (w >> 1) * 64 + mt * 16 + q * 4 + i;
            if (gr < M) {
                #pragma unroll
                for (int nt = 0; nt < 4; nt++) {
                    int gc = col0 + (w & 1) * 64 + nt * 16 + cn;
                    C[(size_t)gr * N + gc] = f2b(acc[mt][nt][i]);
                }
            }
        }
    }
}

// ---------- gather1: max over in-edges + root + bias -> LN -> ReLU -> h (bf16) ----------
// 4x unrolled edge loop: 4 independent 512B gathers in flight per wave.
__global__ __launch_bounds__(256) void gather1(
    const ushort* __restrict__ xw1, const int* __restrict__ offs, const int* __restrict__ ep1,
    const float* __restrict__ bias, const float* __restrict__ g, const float* __restrict__ b,
    ushort* __restrict__ h)
{
    int n = blockIdx.x * 4 + (threadIdx.x >> 6);
    if (n >= NN) return;
    int lane = threadIdx.x & 63;
    int lane4 = lane * 4;
    int e0 = __builtin_amdgcn_readfirstlane(offs[n]);
    int e1 = __builtin_amdgcn_readfirstlane(offs[n + 1]);

    float m0 = -INFINITY, m1 = -INFINITY, m2 = -INFINITY, m3 = -INFINITY;
    int e = e0;
    for (; e + 4 <= e1; e += 4) {
        int p0 = ep1[e + 0], p1 = ep1[e + 1], p2 = ep1[e + 2], p3 = ep1[e + 3];
        ushort4 v0 = *(const ushort4*)&xw1[(size_t)(p0 + lane4)];
        ushort4 v1 = *(const ushort4*)&xw1[(size_t)(p1 + lane4)];
        ushort4 v2 = *(const ushort4*)&xw1[(size_t)(p2 + lane4)];
        ushort4 v3 = *(const ushort4*)&xw1[(size_t)(p3 + lane4)];
        m0 = fmaxf(fmaxf(m0, fmaxf(b2f(v0.x), b2f(v1.x))), fmaxf(b2f(v2.x), b2f(v3.x)));
        m1 = fmaxf(fmaxf(m1, fmaxf(b2f(v0.y), b2f(v1.y))), fmaxf(b2f(v2.y), b2f(v3.y)));
        m2 = fmaxf(fmaxf(m2, fmaxf(b2f(v0.z), b2f(v1.z))), fmaxf(b2f(v2.z), b2f(v3.z)));
        m3 = fmaxf(fmaxf(m3, fmaxf(b2f(v0.w), b2f(v1.w))), fmaxf(b2f(v2.w), b2f(v3.w)));
    }
    for (; e < e1; e++) {
        int p = ep1[e];
        ushort4 v = *(const ushort4*)&xw1[(size_t)(p + lane4)];
        m0 = fmaxf(m0, b2f(v.x)); m1 = fmaxf(m1, b2f(v.y));
        m2 = fmaxf(m2, b2f(v.z)); m3 = fmaxf(m3, b2f(v.w));
    }
    if (e1 == e0) { m0 = m1 = m2 = m3 = 0.f; }   // empty segment -> 0

    ushort4 rt = *(const ushort4*)&xw1[(size_t)n * N1 + NREL * D_HID + lane4];
    int c = lane4;
    float t0 = m0 + b2f(rt.x) + bias[c + 0];
    float t1 = m1 + b2f(rt.y) + bias[c + 1];
    float t2 = m2 + b2f(rt.z) + bias[c + 2];
    float t3 = m3 + b2f(rt.w) + bias[c + 3];

    float s = t0 + t1 + t2 + t3;
    float s2 = t0 * t0 + t1 * t1 + t2 * t2 + t3 * t3;
    #pragma unroll
    for (int m = 32; m >= 1; m >>= 1) {
        s  += __shfl_xor(s,  m, 64);
        s2 += __shfl_xor(s2, m, 64);
    }
    float mu = s * (1.f / D_HID);
    float var = s2 * (1.f / D_HID) - mu * mu;
    float rs = rsqrtf(var + LN_EPS);

    ushort4 o;
    o.x = f2b(fmaxf((t0 - mu) * rs * g[c + 0] + b[c + 0], 0.f));
    o.y = f2b(fmaxf((t1 - mu) * rs * g[c + 1] + b[c + 1], 0.f));
    o.z = f2b(fmaxf((t2 - mu) * rs * g[c + 2] + b[c + 2], 0.f));
    o.w = f2b(fmaxf((t3 - mu) * rs * g[c + 3] + b[c + 3], 0.f));
    *(ushort4*)&h[(size_t)n * D_HID + c] = o;
}

// ---------- gather2: sum over in-edges + root + bias -> LN -> log_softmax -> out (fp32) ----------
__global__ __launch_bounds__(256) void gather2(
    const ushort* __restrict__ xw2, const int* __restrict__ offs, const int* __restrict__ ep2,
    const float* __restrict__ bias, const float* __restrict__ g, const float* __restrict__ b,
    float* __restrict__ out)
{
    int n = blockIdx.x * 4 + (threadIdx.x >> 6);
    if (n >= NN) return;
    int lane = threadIdx.x & 63;
    int e0 = __builtin_amdgcn_readfirstlane(offs[n]);
    int e1 = __builtin_amdgcn_readfirstlane(offs[n + 1]);

    float s = 0.f;
    int e = e0;
    for (; e + 4 <= e1; e += 4) {
        int p0 = ep2[e + 0], p1 = ep2[e + 1], p2 = ep2[e + 2], p3 = ep2[e + 3];
        float a0 = b2f(xw2[(size_t)(p0 + lane)]);
        float a1 = b2f(xw2[(size_t)(p1 + lane)]);
        float a2 = b2f(xw2[(size_t)(p2 + lane)]);
        float a3 = b2f(xw2[(size_t)(p3 + lane)]);
        s += (a0 + a1) + (a2 + a3);
    }
    for (; e < e1; e++) {
        s += b2f(xw2[(size_t)(ep2[e] + lane)]);
    }
    float v = s + b2f(xw2[(size_t)n * N2 + NREL * D_OUT + lane]) + bias[lane];

    float sm = v, s2 = v * v;
    #pragma unroll
    for (int m = 32; m >= 1; m >>= 1) {
        sm += __shfl_xor(sm, m, 64);
        s2 += __shfl_xor(s2, m, 64);
    }
    float mu = sm * (1.f / D_OUT);
    float var = s2 * (1.f / D_OUT) - mu * mu;
    float y = (v - mu) * rsqrtf(var + LN_EPS) * g[lane] + b[lane];

    float mx = y;
    #pragma unroll
    for (int m = 32; m >= 1; m >>= 1) mx = fmaxf(mx, __shfl_xor(mx, m, 64));
    float ex = __expf(y - mx);
    float se = ex;
    #pragma unroll
    for (int m = 32; m >= 1; m >>= 1) se += __shfl_xor(se, m, 64);
    out[(size_t)n * D_OUT + lane] = y - mx - logf(se);
}

extern "C" void kernel_launch(void* const* d_in, const int* in_sizes, int n_in,
                              void* d_out, int out_size, void* d_ws, size_t ws_size,
                              hipStream_t stream)
{
    const float* x      = (const float*)d_in[0];
    const int*   eidx   = (const int*)  d_in[1];
    const int*   etype  = (const int*)  d_in[2];
    const float* bases1 = (const float*)d_in[3];
    const float* comp1  = (const float*)d_in[4];
    const float* root1  = (const float*)d_in[5];
    const float* bias1  = (const float*)d_in[6];
    const float* g1     = (const float*)d_in[7];
    const float* b1     = (const float*)d_in[8];
    const float* bases2 = (const float*)d_in[9];
    const float* comp2  = (const float*)d_in[10];
    const float* root2  = (const float*)d_in[11];
    const float* bias2  = (const float*)d_in[12];
    const float* g2     = (const float*)d_in[13];
    const float* b2     = (const float*)d_in[14];

    const int* src = eidx;
    const int* dst = eidx + NE;

    // workspace carve-up (256B aligned); total ~148 MB
    char* p = (char*)d_ws;
    auto alloc = [&](size_t bytes) -> char* {
        char* r = p;
        p += (bytes + 255) & ~(size_t)255;
        return r;
    };
    ushort* xbf    = (ushort*)alloc((size_t)NN * D_IN * 2);      // 5.1 MB
    ushort* w1t    = (ushort*)alloc((size_t)N1 * D_IN * 2);      // 0.66 MB
    ushort* w2t    = (ushort*)alloc((size_t)N2 * D_HID * 2);     // 0.33 MB
    ushort* xw1    = (ushort*)alloc((size_t)NN * N1 * 2);        // 102.4 MB
    ushort* xw2    = (ushort*)alloc((size_t)NN * N2 * 2);        // 25.6 MB
    ushort* h      = (ushort*)alloc((size_t)NN * D_HID * 2);     // 10.2 MB
    int*    deg    = (int*)   alloc((size_t)NN * 4);
    int*    local  = (int*)   alloc((size_t)NN * 4);
    int*    bsum   = (int*)   alloc((size_t)NBLK * 4);
    int*    boff   = (int*)   alloc((size_t)NBLK * 4);
    int*    offs   = (int*)   alloc((size_t)(NN + 1) * 4);
    int*    cursor = (int*)   alloc((size_t)NN * 4);
    int*    ep1    = (int*)   alloc((size_t)NE * 4);             // 1.3 MB
    int*    ep2    = (int*)   alloc((size_t)NE * 4);             // 1.3 MB

    // prep (weights + x cast) and CSR build
    const int SZP = N1 * D_IN + N2 * D_HID + NN * D_IN;
    prep_all<<<(SZP + 255) / 256, 256, 0, stream>>>(
        bases1, comp1, root1, bases2, comp2, root2, x, w1t, w2t, xbf);

    hipMemsetAsync(deg, 0, (size_t)NN * 4, stream);
    hist_dst<<<(NE + 255) / 256, 256, 0, stream>>>(dst, deg);
    scan_blk<<<NBLK, 256, 0, stream>>>(deg, local, bsum);
    scan_top<<<1, 64, 0, stream>>>(bsum, boff);
    scan_fin<<<NBLK, 256, 0, stream>>>(local, boff, offs, cursor);
    scatter_ep<<<(NE + 255) / 256, 256, 0, stream>>>(src, dst, etype, cursor, ep1, ep2);

    // layer 1: one fused GEMM (9 relations + root), then gather-max + LN + ReLU
    gemm_bf16<<<dim3(N1 / 128, (NN + 127) / 128), 256, 0, stream>>>(xbf, w1t, xw1, NN, N1, D_IN);
    gather1<<<(NN + 3) / 4, 256, 0, stream>>>(xw1, offs, ep1, bias1, g1, b1, h);

    // layer 2: one fused GEMM, then gather-sum + LN + log_softmax
    gemm_bf16<<<dim3(N2 / 128, (NN + 127) / 128), 256, 0, stream>>>(h, w2t, xw2, NN, N2, D_HID);
    gather2<<<(NN + 3) / 4, 256, 0, stream>>>(xw2, offs, ep2, bias2, g2, b2, (float*)d_out);
}